// Round 2
// baseline (8774.899 us; speedup 1.0000x reference)
//
#include <hip/hip_runtime.h>
#include <stdint.h>

#define TT 48
#define HH 180
#define WW 240
#define KCAP 4
#define HWPIX (HH*WW)                   // 43200
#define NSLOTS ((size_t)TT*HWPIX*KCAP)  // 8294400
#define CAP 16384
#define TS_STEP 33333

// ---------------- Kernel 1: per-pixel serial ESIM scan, emit events into value-buckets ----------------
__global__ void scan_kernel(const float* __restrict__ images,
                            uint8_t* __restrict__ npol, uint32_t* __restrict__ bucket_count,
                            uint64_t* __restrict__ keys, uint32_t* __restrict__ meta) {
#pragma clang fp contract(off)
  __shared__ double ts_sh[TT];
  int tid = threadIdx.x;
  if (tid < TT) ts_sh[tid] = (double)(tid * TS_STEP);   // timestamps are statically i*33333 (exact)
  __syncthreads();
  int p = blockIdx.x * blockDim.x + tid;
  if (p >= HWPIX) return;

  float ref = images[p];        // init_ref = images[0]
  float img_prev = ref;
  for (int t = 0; t < TT; ++t) {
    float img = images[(size_t)t * HWPIX + p];
    float diff = img - ref;
    float pol = (diff > 0.0f) ? 1.0f : ((diff < 0.0f) ? -1.0f : 0.0f);
    float n = floorf(fabsf(diff) / 0.2f);     // IEEE float div, matches jnp
    int ni = (int)n;
    int pc = (pol > 0.0f) ? 1 : ((pol < 0.0f) ? 2 : 0);
    npol[(size_t)t * HWPIX + p] = (uint8_t)(ni | (pc << 3));

    if (ni > 0) {
      float denom = img - img_prev;
      double tsprev = ts_sh[t - 1];           // ni>0 only possible for t>=1
      double delta = ts_sh[t] - tsprev;
      for (int k = 1; k <= ni; ++k) {
        float kct = (float)k * 0.2f;          // (pol*k)*CT magnitude; pol=+-1 exact
        float v = ref + pol * kct;            // crossed level (no FMA)
        float qv = v - img_prev;
        float frac = (denom == 0.0f) ? 0.0f : (qv / denom);
        double prod = (double)frac * delta;   // no FMA
        double t_ev = tsprev + prod;

        // bucket by VALUE: robust to frac<0 or frac>1 rounding stragglers
        int b = t;
        while (b > 0 && t_ev <= ts_sh[b - 1]) --b;
        while (b < TT - 1 && t_ev > ts_sh[b]) ++b;

        uint32_t slot = atomicAdd(&bucket_count[b], 1u);
        if (slot < CAP) {
          uint64_t ub = (uint64_t)__double_as_longlong(t_ev);
          uint64_t key = (ub & 0x8000000000000000ULL) ? ~ub : (ub ^ 0x8000000000000000ULL);
          uint32_t gidx = (((uint32_t)t * HWPIX + (uint32_t)p) << 2) + (uint32_t)(k - 1); // flat idx < 2^23
          uint32_t mm = gidx | ((pol < 0.0f ? 1u : 0u) << 23);
          keys[(size_t)b * CAP + slot] = key;
          meta[(size_t)b * CAP + slot] = mm;
        }
      }
    }
    float nct = n * 0.2f;
    ref = ref + pol * nct;                    // new_ref (no FMA)
    img_prev = img;
  }
}

// ---------------- Kernel 2: per-frame exclusive prefix sum of event counts over pixels ----------------
__global__ void pixel_prefix(const uint8_t* __restrict__ npol, uint32_t* __restrict__ pixpre,
                             uint32_t* __restrict__ frame_total) {
  int f = blockIdx.x, tid = threadIdx.x;
  __shared__ uint32_t sh[256];
  uint32_t run = 0;
  const uint8_t* np = npol + (size_t)f * HWPIX;
  uint32_t* pp = pixpre + (size_t)f * HWPIX;
  for (int b0 = 0; b0 < HWPIX; b0 += 256) {
    int i = b0 + tid;
    uint32_t v = (i < HWPIX) ? (uint32_t)(np[i] & 7u) : 0u;
    sh[tid] = v;
    __syncthreads();
    for (int offd = 1; offd < 256; offd <<= 1) {
      uint32_t x = (tid >= offd) ? sh[tid - offd] : 0u;
      __syncthreads();
      sh[tid] += x;
      __syncthreads();
    }
    if (i < HWPIX) pp[i] = run + sh[tid] - v;   // exclusive prefix
    run += sh[255];
    __syncthreads();
  }
  if (tid == 0) frame_total[f] = run;
}

// ---------------- Kernel 3: tiny serial scans (48 elements each) ----------------
__global__ void small_scans(const uint32_t* __restrict__ bucket_count, uint32_t* __restrict__ bucket_base,
                            const uint32_t* __restrict__ frame_total, uint32_t* __restrict__ frame_base) {
  if (threadIdx.x == 0 && blockIdx.x == 0) {
    uint32_t s = 0;
    for (int i = 0; i < TT; ++i) {
      bucket_base[i] = s;
      uint32_t c = bucket_count[i]; if (c > CAP) c = CAP;
      s += c;
    }
    bucket_base[TT] = s;
    s = 0;
    for (int i = 0; i < TT; ++i) { frame_base[i] = s; s += frame_total[i]; }
    frame_base[TT] = s;
  }
}

// ---------------- Kernel 4: per-bucket brute-force stable rank + scatter valid events ----------------
__global__ void rank_scatter(const uint64_t* __restrict__ keys, const uint32_t* __restrict__ meta,
                             const uint32_t* __restrict__ bucket_count, const uint32_t* __restrict__ bucket_base,
                             int32_t* __restrict__ out) {
  int b = blockIdx.y;
  uint32_t m = bucket_count[b]; if (m > CAP) m = CAP;
  if (blockIdx.x * blockDim.x >= m) return;
  __shared__ uint64_t sk[256];
  __shared__ uint32_t sm[256];
  uint32_t e = blockIdx.x * blockDim.x + threadIdx.x;
  bool have = e < m;
  uint64_t myk = 0; uint32_t mym = 0;
  if (have) { myk = keys[(size_t)b * CAP + e]; mym = meta[(size_t)b * CAP + e]; }
  uint32_t myidx = mym & 0x7FFFFFu;
  uint32_t rank = 0;
  for (uint32_t j0 = 0; j0 < m; j0 += 256) {
    uint32_t j = j0 + threadIdx.x;
    if (j < m) { sk[threadIdx.x] = keys[(size_t)b * CAP + j]; sm[threadIdx.x] = meta[(size_t)b * CAP + j]; }
    __syncthreads();
    uint32_t lim = min(256u, m - j0);
    if (have) {
      for (uint32_t jj = 0; jj < lim; ++jj) {
        uint64_t kj = sk[jj];
        bool less = (kj < myk) || (kj == myk && (sm[jj] & 0x7FFFFFu) < myidx);
        rank += (uint32_t)less;
      }
    }
    __syncthreads();
  }
  if (have) {
    uint32_t pos = bucket_base[b] + rank;
    uint64_t ub = (myk & 0x8000000000000000ULL) ? (myk ^ 0x8000000000000000ULL) : ~myk;
    double t_ev = __longlong_as_double((long long)ub);
    uint32_t pix = (myidx >> 2) % HWPIX;
    uint32_t x = pix % WW, y = pix / WW;
    int32_t pval = ((mym >> 23) & 1u) ? -1 : 1;
    long long ti = (long long)t_ev;           // truncation == astype(int64) for t_ev >= 0
    out[pos]              = (int32_t)x;
    out[NSLOTS + pos]     = (int32_t)y;
    out[2 * NSLOTS + pos] = (int32_t)ti;
    out[3 * NSLOTS + pos] = pval;
    out[4 * NSLOTS + pos] = 1;
  }
}

// ---------------- Kernel 5: invalid slots -> tail, original flat order ----------------
__global__ void invalid_scatter(const uint8_t* __restrict__ npol, const uint32_t* __restrict__ pixpre,
                                const uint32_t* __restrict__ frame_base, int32_t* __restrict__ out) {
  uint32_t s = blockIdx.x * blockDim.x + threadIdx.x;
  if (s >= (uint32_t)NSLOTS) return;
  uint32_t k = (s & 3u) + 1u;
  uint32_t tp = s >> 2;
  uint32_t t = tp / HWPIX;
  uint32_t pix = tp - t * HWPIX;
  uint8_t bb = npol[tp];
  uint32_t n = bb & 7u;
  if (k <= n) return;                          // valid slot, handled by rank_scatter
  uint32_t nvalid_total = frame_base[TT];
  uint32_t vb = frame_base[t] + pixpre[tp] + min(k - 1u, n);  // #valid with flat idx < s
  uint32_t pos = nvalid_total + (s - vb);
  uint32_t x = pix % WW, y = pix / WW;
  uint32_t pc = (bb >> 3) & 3u;
  int32_t pval = (pc == 1u) ? 1 : ((pc == 2u) ? -1 : 0);
  out[pos]              = (int32_t)x;
  out[NSLOTS + pos]     = (int32_t)y;
  out[2 * NSLOTS + pos] = 0;
  out[3 * NSLOTS + pos] = pval;
  out[4 * NSLOTS + pos] = 0;
}

extern "C" void kernel_launch(void* const* d_in, const int* in_sizes, int n_in,
                              void* d_out, int out_size, void* d_ws, size_t ws_size,
                              hipStream_t stream) {
  const float* images = (const float*)d_in[0];
  int32_t* out = (int32_t*)d_out;

  uint8_t* base = (uint8_t*)d_ws;
  size_t off = 0;
  auto carve = [&](size_t bytes, size_t align) -> void* {
    off = (off + align - 1) & ~(align - 1);
    void* p = base + off; off += bytes; return p;
  };
  uint32_t* bucket_count = (uint32_t*)carve(TT * 4, 256);
  uint32_t* bucket_base  = (uint32_t*)carve((TT + 1) * 4, 256);
  uint32_t* frame_total  = (uint32_t*)carve(TT * 4, 256);
  uint32_t* frame_base   = (uint32_t*)carve((TT + 1) * 4, 256);
  uint8_t*  npol         = (uint8_t*) carve((size_t)TT * HWPIX, 256);
  uint32_t* pixpre       = (uint32_t*)carve((size_t)TT * HWPIX * 4, 256);
  uint64_t* keys         = (uint64_t*)carve((size_t)TT * CAP * 8, 256);
  uint32_t* meta         = (uint32_t*)carve((size_t)TT * CAP * 4, 256);
  (void)ws_size; (void)out_size; (void)in_sizes; (void)n_in;

  hipMemsetAsync(bucket_count, 0, TT * 4, stream);
  scan_kernel<<<(HWPIX + 255) / 256, 256, 0, stream>>>(images, npol, bucket_count, keys, meta);
  pixel_prefix<<<TT, 256, 0, stream>>>(npol, pixpre, frame_total);
  small_scans<<<1, 64, 0, stream>>>(bucket_count, bucket_base, frame_total, frame_base);
  dim3 g4(CAP / 256, TT);
  rank_scatter<<<g4, 256, 0, stream>>>(keys, meta, bucket_count, bucket_base, out);
  invalid_scatter<<<(uint32_t)((NSLOTS + 255) / 256), 256, 0, stream>>>(npol, pixpre, frame_base, out);
}

// Round 4
// 2309.659 us; speedup vs baseline: 3.7992x; 3.7992x over previous
//
#include <hip/hip_runtime.h>
#include <stdint.h>

#define TT 48
#define HH 180
#define WW 240
#define KCAP 4
#define HWPIX (HH*WW)                   // 43200
#define NSLOTS ((size_t)TT*HWPIX*KCAP)  // 8294400
#define CAP 16384
#define TS_STEP 33333

// ---------------- Kernel 1: per-pixel serial ESIM scan, lockstep frames, LDS-aggregated slot reservation ----------------
// Fast path: bucket b in {t-1,t,t+1} -> LDS counter aggregation, 1 global atomic per (WG,bucket).
// Rare path: frac << 0 (tiny denom + ref/img_prev residual) -> bucket far below t -> per-event global atomic.
__global__ void scan_kernel(const float* __restrict__ images,
                            uint8_t* __restrict__ npol, uint32_t* __restrict__ bucket_count,
                            uint64_t* __restrict__ keys, uint32_t* __restrict__ meta) {
#pragma clang fp contract(off)
  __shared__ uint32_t lcnt[4];
  __shared__ uint32_t gbase[4];
  int tid = threadIdx.x;
  int p = blockIdx.x * blockDim.x + tid;
  bool active = p < HWPIX;

  float ref = 0.0f, img_prev = 0.0f;
  if (active) { ref = images[p]; img_prev = ref; }   // init_ref = images[0]

  for (int t = 0; t < TT; ++t) {
    if (tid < 4) lcnt[tid] = 0;
    __syncthreads();

    int ni = 0;
    float pol = 0.0f;
    uint64_t ek[KCAP]; uint32_t em[KCAP]; uint32_t eli[KCAP]; uint32_t esl[KCAP]; int eb[KCAP];

    if (active) {
      float img = images[(size_t)t * HWPIX + p];
      float diff = img - ref;
      pol = (diff > 0.0f) ? 1.0f : ((diff < 0.0f) ? -1.0f : 0.0f);
      float n = floorf(fabsf(diff) / 0.2f);     // IEEE float div, matches jnp
      ni = (int)n;
      int pc = (pol > 0.0f) ? 1 : ((pol < 0.0f) ? 2 : 0);
      npol[(size_t)t * HWPIX + p] = (uint8_t)(ni | (pc << 3));

      if (ni > 0) {                              // only possible for t >= 1
        float denom = img - img_prev;
        double tsprev = (double)((t - 1) * TS_STEP);   // exact
        double delta = (double)TS_STEP;                // exact
#pragma unroll
        for (int k = 1; k <= KCAP; ++k) {
          if (k <= ni) {
            float kct = (float)k * 0.2f;
            float v = ref + pol * kct;           // crossed level (no FMA)
            float qv = v - img_prev;
            float frac = (denom == 0.0f) ? 0.0f : (qv / denom);
            double t_ev = tsprev + (double)frac * delta;   // no FMA

            // bucket by VALUE: first b with ts[b-1] < t_ev <= ts[b]; frac can be << 0!
            int b = t;
            while (b > 0 && t_ev <= (double)((b - 1) * TS_STEP)) --b;
            while (b < TT - 1 && t_ev > (double)(b * TS_STEP)) ++b;

            uint64_t ub = (uint64_t)__double_as_longlong(t_ev);
            uint64_t key = (ub & 0x8000000000000000ULL) ? ~ub : (ub ^ 0x8000000000000000ULL);
            uint32_t gidx = (((uint32_t)t * HWPIX + (uint32_t)p) << 2) + (uint32_t)(k - 1);
            ek[k - 1] = key;
            em[k - 1] = gidx | ((pol < 0.0f ? 1u : 0u) << 23);
            eb[k - 1] = b;
            int li = b - (t - 1);
            if (li >= 0 && li <= 2) {
              eli[k - 1] = (uint32_t)li;
              esl[k - 1] = atomicAdd(&lcnt[li], 1u);            // LDS atomic: fast
            } else {
              eli[k - 1] = 3u;                                   // rare far-bucket fallback
              esl[k - 1] = atomicAdd(&bucket_count[b], 1u);      // per-event global atomic
            }
          }
        }
      }
      float nct = n * 0.2f;
      ref = ref + pol * nct;                    // new_ref (no FMA)
      img_prev = img;
    }
    __syncthreads();

    if (tid < 3) {                               // one global atomic per (WG, near-bucket)
      int b = t - 1 + tid;
      uint32_t c = lcnt[tid];
      uint32_t g = 0;
      if (c > 0 && b >= 0 && b < TT) g = atomicAdd(&bucket_count[b], c);
      gbase[tid] = g;
    }
    __syncthreads();

#pragma unroll
    for (int k = 0; k < KCAP; ++k) {
      if (k < ni) {
        uint32_t li = eli[k];
        uint32_t s = (li == 3u) ? esl[k] : (gbase[li] + esl[k]);
        int b = eb[k];
        if (s < CAP) {
          keys[(size_t)b * CAP + s] = ek[k];
          meta[(size_t)b * CAP + s] = em[k];
        }
      }
    }
  }
}

// ---------------- Kernel 2: per-frame exclusive prefix sum of event counts over pixels ----------------
__global__ void pixel_prefix(const uint8_t* __restrict__ npol, uint32_t* __restrict__ pixpre,
                             uint32_t* __restrict__ frame_total) {
  int f = blockIdx.x, tid = threadIdx.x;
  __shared__ uint32_t sh[256];
  uint32_t run = 0;
  const uint8_t* np = npol + (size_t)f * HWPIX;
  uint32_t* pp = pixpre + (size_t)f * HWPIX;
  for (int b0 = 0; b0 < HWPIX; b0 += 256) {
    int i = b0 + tid;
    uint32_t v = (i < HWPIX) ? (uint32_t)(np[i] & 7u) : 0u;
    sh[tid] = v;
    __syncthreads();
    for (int offd = 1; offd < 256; offd <<= 1) {
      uint32_t x = (tid >= offd) ? sh[tid - offd] : 0u;
      __syncthreads();
      sh[tid] += x;
      __syncthreads();
    }
    if (i < HWPIX) pp[i] = run + sh[tid] - v;   // exclusive prefix
    run += sh[255];
    __syncthreads();
  }
  if (tid == 0) frame_total[f] = run;
}

// ---------------- Kernel 3: tiny serial scans (48 elements each) ----------------
__global__ void small_scans(const uint32_t* __restrict__ bucket_count, uint32_t* __restrict__ bucket_base,
                            const uint32_t* __restrict__ frame_total, uint32_t* __restrict__ frame_base) {
  if (threadIdx.x == 0 && blockIdx.x == 0) {
    uint32_t s = 0;
    for (int i = 0; i < TT; ++i) {
      bucket_base[i] = s;
      uint32_t c = bucket_count[i]; if (c > CAP) c = CAP;
      s += c;
    }
    bucket_base[TT] = s;
    s = 0;
    for (int i = 0; i < TT; ++i) { frame_base[i] = s; s += frame_total[i]; }
    frame_base[TT] = s;
  }
}

// ---------------- Kernel 4: per-bucket brute-force stable rank + scatter valid events ----------------
__global__ void rank_scatter(const uint64_t* __restrict__ keys, const uint32_t* __restrict__ meta,
                             const uint32_t* __restrict__ bucket_count, const uint32_t* __restrict__ bucket_base,
                             int32_t* __restrict__ out) {
  int b = blockIdx.y;
  uint32_t m = bucket_count[b]; if (m > CAP) m = CAP;
  if (blockIdx.x * blockDim.x >= m) return;
  __shared__ uint64_t sk[256];
  __shared__ uint32_t sm[256];
  uint32_t e = blockIdx.x * blockDim.x + threadIdx.x;
  bool have = e < m;
  uint64_t myk = 0; uint32_t mym = 0;
  if (have) { myk = keys[(size_t)b * CAP + e]; mym = meta[(size_t)b * CAP + e]; }
  uint32_t myidx = mym & 0x7FFFFFu;
  uint32_t rank = 0;
  for (uint32_t j0 = 0; j0 < m; j0 += 256) {
    uint32_t j = j0 + threadIdx.x;
    if (j < m) { sk[threadIdx.x] = keys[(size_t)b * CAP + j]; sm[threadIdx.x] = meta[(size_t)b * CAP + j]; }
    __syncthreads();
    uint32_t lim = min(256u, m - j0);
    if (have) {
#pragma unroll 8
      for (uint32_t jj = 0; jj < lim; ++jj) {
        uint64_t kj = sk[jj];
        bool less = (kj < myk) || (kj == myk && (sm[jj] & 0x7FFFFFu) < myidx);
        rank += (uint32_t)less;
      }
    }
    __syncthreads();
  }
  if (have) {
    uint32_t pos = bucket_base[b] + rank;
    uint64_t ub = (myk & 0x8000000000000000ULL) ? (myk ^ 0x8000000000000000ULL) : ~myk;
    double t_ev = __longlong_as_double((long long)ub);
    uint32_t pix = (myidx >> 2) % HWPIX;
    uint32_t x = pix % WW, y = pix / WW;
    int32_t pval = ((mym >> 23) & 1u) ? -1 : 1;
    long long ti = (long long)t_ev;           // trunc-toward-zero == astype(int64)
    out[pos]              = (int32_t)x;
    out[NSLOTS + pos]     = (int32_t)y;
    out[2 * NSLOTS + pos] = (int32_t)ti;
    out[3 * NSLOTS + pos] = pval;
    out[4 * NSLOTS + pos] = 1;
  }
}

// ---------------- Kernel 5: invalid slots -> tail, original flat order ----------------
__global__ void invalid_scatter(const uint8_t* __restrict__ npol, const uint32_t* __restrict__ pixpre,
                                const uint32_t* __restrict__ frame_base, int32_t* __restrict__ out) {
  uint32_t s = blockIdx.x * blockDim.x + threadIdx.x;
  if (s >= (uint32_t)NSLOTS) return;
  uint32_t k = (s & 3u) + 1u;
  uint32_t tp = s >> 2;
  uint32_t t = tp / HWPIX;
  uint32_t pix = tp - t * HWPIX;
  uint8_t bb = npol[tp];
  uint32_t n = bb & 7u;
  if (k <= n) return;                          // valid slot, handled by rank_scatter
  uint32_t nvalid_total = frame_base[TT];
  uint32_t vb = frame_base[t] + pixpre[tp] + min(k - 1u, n);  // #valid with flat idx < s
  uint32_t pos = nvalid_total + (s - vb);
  uint32_t x = pix % WW, y = pix / WW;
  uint32_t pc = (bb >> 3) & 3u;
  int32_t pval = (pc == 1u) ? 1 : ((pc == 2u) ? -1 : 0);
  out[pos]              = (int32_t)x;
  out[NSLOTS + pos]     = (int32_t)y;
  out[2 * NSLOTS + pos] = 0;
  out[3 * NSLOTS + pos] = pval;
  out[4 * NSLOTS + pos] = 0;
}

extern "C" void kernel_launch(void* const* d_in, const int* in_sizes, int n_in,
                              void* d_out, int out_size, void* d_ws, size_t ws_size,
                              hipStream_t stream) {
  const float* images = (const float*)d_in[0];
  int32_t* out = (int32_t*)d_out;

  uint8_t* base = (uint8_t*)d_ws;
  size_t off = 0;
  auto carve = [&](size_t bytes, size_t align) -> void* {
    off = (off + align - 1) & ~(align - 1);
    void* p = base + off; off += bytes; return p;
  };
  uint32_t* bucket_count = (uint32_t*)carve(TT * 4, 256);
  uint32_t* bucket_base  = (uint32_t*)carve((TT + 1) * 4, 256);
  uint32_t* frame_total  = (uint32_t*)carve(TT * 4, 256);
  uint32_t* frame_base   = (uint32_t*)carve((TT + 1) * 4, 256);
  uint8_t*  npol         = (uint8_t*) carve((size_t)TT * HWPIX, 256);
  uint32_t* pixpre       = (uint32_t*)carve((size_t)TT * HWPIX * 4, 256);
  uint64_t* keys         = (uint64_t*)carve((size_t)TT * CAP * 8, 256);
  uint32_t* meta         = (uint32_t*)carve((size_t)TT * CAP * 4, 256);
  (void)ws_size; (void)out_size; (void)in_sizes; (void)n_in;

  hipMemsetAsync(bucket_count, 0, TT * 4, stream);
  scan_kernel<<<(HWPIX + 255) / 256, 256, 0, stream>>>(images, npol, bucket_count, keys, meta);
  pixel_prefix<<<TT, 256, 0, stream>>>(npol, pixpre, frame_total);
  small_scans<<<1, 64, 0, stream>>>(bucket_count, bucket_base, frame_total, frame_base);
  dim3 g4(CAP / 256, TT);
  rank_scatter<<<g4, 256, 0, stream>>>(keys, meta, bucket_count, bucket_base, out);
  invalid_scatter<<<(uint32_t)((NSLOTS + 255) / 256), 256, 0, stream>>>(npol, pixpre, frame_base, out);
}

// Round 5
// 558.047 us; speedup vs baseline: 15.7243x; 4.1388x over previous
//
#include <hip/hip_runtime.h>
#include <stdint.h>

#define TT 48
#define HH 180
#define WW 240
#define KCAP 4
#define HWPIX (HH*WW)                   // 43200
#define NSLOTS ((size_t)TT*HWPIX*KCAP)  // 8294400
#define CAP 16384
#define TS_STEP 33333

// ---------------- Kernel 1: per-pixel serial ESIM scan, lockstep frames, LDS-aggregated slot reservation ----------------
// Fast path: bucket b in {t-1,t,t+1} -> LDS counter aggregation, 1 global atomic per (WG,bucket).
// Rare path: frac << 0 (tiny denom + ref/img_prev residual) -> bucket far below t -> per-event global atomic.
__global__ void scan_kernel(const float* __restrict__ images,
                            uint8_t* __restrict__ npol, uint32_t* __restrict__ bucket_count,
                            uint64_t* __restrict__ keys, uint32_t* __restrict__ meta) {
#pragma clang fp contract(off)
  __shared__ uint32_t lcnt[4];
  __shared__ uint32_t gbase[4];
  int tid = threadIdx.x;
  int p = blockIdx.x * blockDim.x + tid;
  bool active = p < HWPIX;

  float ref = 0.0f, img_prev = 0.0f;
  if (active) { ref = images[p]; img_prev = ref; }   // init_ref = images[0]

  for (int t = 0; t < TT; ++t) {
    if (tid < 4) lcnt[tid] = 0;
    __syncthreads();

    int ni = 0;
    float pol = 0.0f;
    uint64_t ek[KCAP]; uint32_t em[KCAP]; uint32_t eli[KCAP]; uint32_t esl[KCAP]; int eb[KCAP];

    if (active) {
      float img = images[(size_t)t * HWPIX + p];
      float diff = img - ref;
      pol = (diff > 0.0f) ? 1.0f : ((diff < 0.0f) ? -1.0f : 0.0f);
      float n = floorf(fabsf(diff) / 0.2f);     // IEEE float div, matches jnp
      ni = (int)n;
      int pc = (pol > 0.0f) ? 1 : ((pol < 0.0f) ? 2 : 0);
      npol[(size_t)t * HWPIX + p] = (uint8_t)(ni | (pc << 3));

      if (ni > 0) {                              // only possible for t >= 1
        float denom = img - img_prev;
        double tsprev = (double)((t - 1) * TS_STEP);   // exact
        double delta = (double)TS_STEP;                // exact
#pragma unroll
        for (int k = 1; k <= KCAP; ++k) {
          if (k <= ni) {
            float kct = (float)k * 0.2f;
            float v = ref + pol * kct;           // crossed level (no FMA)
            float qv = v - img_prev;
            float frac = (denom == 0.0f) ? 0.0f : (qv / denom);
            double t_ev = tsprev + (double)frac * delta;   // no FMA

            // bucket by VALUE: first b with ts[b-1] < t_ev <= ts[b]; frac can be << 0!
            int b = t;
            while (b > 0 && t_ev <= (double)((b - 1) * TS_STEP)) --b;
            while (b < TT - 1 && t_ev > (double)(b * TS_STEP)) ++b;

            uint64_t ub = (uint64_t)__double_as_longlong(t_ev);
            uint64_t key = (ub & 0x8000000000000000ULL) ? ~ub : (ub ^ 0x8000000000000000ULL);
            uint32_t gidx = (((uint32_t)t * HWPIX + (uint32_t)p) << 2) + (uint32_t)(k - 1);
            ek[k - 1] = key;
            em[k - 1] = gidx | ((pol < 0.0f ? 1u : 0u) << 23);
            eb[k - 1] = b;
            int li = b - (t - 1);
            if (li >= 0 && li <= 2) {
              eli[k - 1] = (uint32_t)li;
              esl[k - 1] = atomicAdd(&lcnt[li], 1u);            // LDS atomic: fast
            } else {
              eli[k - 1] = 3u;                                   // rare far-bucket fallback
              esl[k - 1] = atomicAdd(&bucket_count[b], 1u);      // per-event global atomic
            }
          }
        }
      }
      float nct = n * 0.2f;
      ref = ref + pol * nct;                    // new_ref (no FMA)
      img_prev = img;
    }
    __syncthreads();

    if (tid < 3) {                               // one global atomic per (WG, near-bucket)
      int b = t - 1 + tid;
      uint32_t c = lcnt[tid];
      uint32_t g = 0;
      if (c > 0 && b >= 0 && b < TT) g = atomicAdd(&bucket_count[b], c);
      gbase[tid] = g;
    }
    __syncthreads();

#pragma unroll
    for (int k = 0; k < KCAP; ++k) {
      if (k < ni) {
        uint32_t li = eli[k];
        uint32_t s = (li == 3u) ? esl[k] : (gbase[li] + esl[k]);
        int b = eb[k];
        if (s < CAP) {
          keys[(size_t)b * CAP + s] = ek[k];
          meta[(size_t)b * CAP + s] = em[k];
        }
      }
    }
  }
}

// ---------------- Kernel 2: per-frame exclusive prefix sum of event counts over pixels ----------------
__global__ void pixel_prefix(const uint8_t* __restrict__ npol, uint32_t* __restrict__ pixpre,
                             uint32_t* __restrict__ frame_total) {
  int f = blockIdx.x, tid = threadIdx.x;
  __shared__ uint32_t sh[256];
  uint32_t run = 0;
  const uint8_t* np = npol + (size_t)f * HWPIX;
  uint32_t* pp = pixpre + (size_t)f * HWPIX;
  for (int b0 = 0; b0 < HWPIX; b0 += 256) {
    int i = b0 + tid;
    uint32_t v = (i < HWPIX) ? (uint32_t)(np[i] & 7u) : 0u;
    sh[tid] = v;
    __syncthreads();
    for (int offd = 1; offd < 256; offd <<= 1) {
      uint32_t x = (tid >= offd) ? sh[tid - offd] : 0u;
      __syncthreads();
      sh[tid] += x;
      __syncthreads();
    }
    if (i < HWPIX) pp[i] = run + sh[tid] - v;   // exclusive prefix
    run += sh[255];
    __syncthreads();
  }
  if (tid == 0) frame_total[f] = run;
}

// ---------------- Kernel 3: tiny serial scans (48 elements each) ----------------
__global__ void small_scans(const uint32_t* __restrict__ bucket_count, uint32_t* __restrict__ bucket_base,
                            const uint32_t* __restrict__ frame_total, uint32_t* __restrict__ frame_base) {
  if (threadIdx.x == 0 && blockIdx.x == 0) {
    uint32_t s = 0;
    for (int i = 0; i < TT; ++i) {
      bucket_base[i] = s;
      uint32_t c = bucket_count[i]; if (c > CAP) c = CAP;
      s += c;
    }
    bucket_base[TT] = s;
    s = 0;
    for (int i = 0; i < TT; ++i) { frame_base[i] = s; s += frame_total[i]; }
    frame_base[TT] = s;
  }
}

// ---------------- Kernel 4a: bitonic-sort each 256-element tile of each bucket in-place (by key, tie gidx) ----------------
__global__ void sort_tiles(uint64_t* __restrict__ keys, uint32_t* __restrict__ meta,
                           const uint32_t* __restrict__ bucket_count) {
  int b = blockIdx.y;
  uint32_t m = bucket_count[b]; if (m > CAP) m = CAP;
  uint32_t ntiles = (m + 255u) >> 8;
  if (blockIdx.x >= ntiles) return;
  __shared__ uint64_t sk[256];
  __shared__ uint32_t sm[256];
  int tid = threadIdx.x;
  uint32_t e = blockIdx.x * 256u + (uint32_t)tid;
  bool have = e < m;
  sk[tid] = have ? keys[(size_t)b * CAP + e] : ~0ULL;      // sentinel > any real key (real key never all-ones)
  sm[tid] = have ? meta[(size_t)b * CAP + e] : 0x7FFFFFu;
  __syncthreads();
  for (int kk = 2; kk <= 256; kk <<= 1) {
    for (int j = kk >> 1; j > 0; j >>= 1) {
      int l = tid ^ j;
      if (l > tid) {
        uint64_t ka = sk[tid], kb = sk[l];
        uint32_t ma = sm[tid], mb = sm[l];
        uint32_t ia = ma & 0x7FFFFFu, ib = mb & 0x7FFFFFu;
        bool a_gt = (ka > kb) || (ka == kb && ia > ib);
        bool a_lt = (ka < kb) || (ka == kb && ia < ib);
        bool desc = (tid & kk) != 0;
        bool dosw = desc ? a_lt : a_gt;
        if (dosw) { sk[tid] = kb; sk[l] = ka; sm[tid] = mb; sm[l] = ma; }
      }
      __syncthreads();
    }
  }
  keys[(size_t)b * CAP + e] = sk[tid];   // e < CAP always; slots >= m never read downstream
  meta[(size_t)b * CAP + e] = sm[tid];
}

// ---------------- Kernel 4b: rank via per-tile binary search (tiles sorted), then scatter valid events ----------------
__global__ void rank_scatter(const uint64_t* __restrict__ keys, const uint32_t* __restrict__ meta,
                             const uint32_t* __restrict__ bucket_count, const uint32_t* __restrict__ bucket_base,
                             int32_t* __restrict__ out) {
  int b = blockIdx.y;
  uint32_t m = bucket_count[b]; if (m > CAP) m = CAP;
  uint32_t ntiles = (m + 255u) >> 8;
  if (blockIdx.x >= ntiles) return;
  __shared__ uint64_t sk[256];
  __shared__ uint32_t sm[256];
  uint32_t e = blockIdx.x * 256u + threadIdx.x;
  bool have = e < m;
  uint64_t myk = 0; uint32_t mym = 0;
  if (have) { myk = keys[(size_t)b * CAP + e]; mym = meta[(size_t)b * CAP + e]; }
  uint32_t myidx = mym & 0x7FFFFFu;
  uint32_t rank = 0;
  for (uint32_t t2 = 0; t2 < ntiles; ++t2) {
    uint32_t j = t2 * 256u + threadIdx.x;
    sk[threadIdx.x] = (j < m) ? keys[(size_t)b * CAP + j] : ~0ULL;
    sm[threadIdx.x] = (j < m) ? meta[(size_t)b * CAP + j] : 0x7FFFFFu;
    __syncthreads();
    if (have) {
      // lower_bound of (myk, myidx) in sorted 256-tile; sentinels never counted
      uint32_t lo = 0, hi = 256;
      while (lo < hi) {
        uint32_t mid = (lo + hi) >> 1;
        uint64_t kj = sk[mid];
        uint32_t ij = sm[mid] & 0x7FFFFFu;
        bool less = (kj < myk) || (kj == myk && ij < myidx);
        lo = less ? mid + 1u : lo;
        hi = less ? hi : mid;
      }
      rank += lo;     // own tile contributes exactly my in-tile position
    }
    __syncthreads();
  }
  if (have) {
    uint32_t pos = bucket_base[b] + rank;
    uint64_t ub = (myk & 0x8000000000000000ULL) ? (myk ^ 0x8000000000000000ULL) : ~myk;
    double t_ev = __longlong_as_double((long long)ub);
    uint32_t pix = (myidx >> 2) % HWPIX;
    uint32_t x = pix % WW, y = pix / WW;
    int32_t pval = ((mym >> 23) & 1u) ? -1 : 1;
    long long ti = (long long)t_ev;           // trunc-toward-zero == astype(int64) for t_ev >= 0
    out[pos]              = (int32_t)x;
    out[NSLOTS + pos]     = (int32_t)y;
    out[2 * NSLOTS + pos] = (int32_t)ti;
    out[3 * NSLOTS + pos] = pval;
    out[4 * NSLOTS + pos] = 1;
  }
}

// ---------------- Kernel 5: invalid slots -> tail, original flat order ----------------
__global__ void invalid_scatter(const uint8_t* __restrict__ npol, const uint32_t* __restrict__ pixpre,
                                const uint32_t* __restrict__ frame_base, int32_t* __restrict__ out) {
  uint32_t s = blockIdx.x * blockDim.x + threadIdx.x;
  if (s >= (uint32_t)NSLOTS) return;
  uint32_t k = (s & 3u) + 1u;
  uint32_t tp = s >> 2;
  uint32_t t = tp / HWPIX;
  uint32_t pix = tp - t * HWPIX;
  uint8_t bb = npol[tp];
  uint32_t n = bb & 7u;
  if (k <= n) return;                          // valid slot, handled by rank_scatter
  uint32_t nvalid_total = frame_base[TT];
  uint32_t vb = frame_base[t] + pixpre[tp] + min(k - 1u, n);  // #valid with flat idx < s
  uint32_t pos = nvalid_total + (s - vb);
  uint32_t x = pix % WW, y = pix / WW;
  uint32_t pc = (bb >> 3) & 3u;
  int32_t pval = (pc == 1u) ? 1 : ((pc == 2u) ? -1 : 0);
  out[pos]              = (int32_t)x;
  out[NSLOTS + pos]     = (int32_t)y;
  out[2 * NSLOTS + pos] = 0;
  out[3 * NSLOTS + pos] = pval;
  out[4 * NSLOTS + pos] = 0;
}

extern "C" void kernel_launch(void* const* d_in, const int* in_sizes, int n_in,
                              void* d_out, int out_size, void* d_ws, size_t ws_size,
                              hipStream_t stream) {
  const float* images = (const float*)d_in[0];
  int32_t* out = (int32_t*)d_out;

  uint8_t* base = (uint8_t*)d_ws;
  size_t off = 0;
  auto carve = [&](size_t bytes, size_t align) -> void* {
    off = (off + align - 1) & ~(align - 1);
    void* p = base + off; off += bytes; return p;
  };
  uint32_t* bucket_count = (uint32_t*)carve(TT * 4, 256);
  uint32_t* bucket_base  = (uint32_t*)carve((TT + 1) * 4, 256);
  uint32_t* frame_total  = (uint32_t*)carve(TT * 4, 256);
  uint32_t* frame_base   = (uint32_t*)carve((TT + 1) * 4, 256);
  uint8_t*  npol         = (uint8_t*) carve((size_t)TT * HWPIX, 256);
  uint32_t* pixpre       = (uint32_t*)carve((size_t)TT * HWPIX * 4, 256);
  uint64_t* keys         = (uint64_t*)carve((size_t)TT * CAP * 8, 256);
  uint32_t* meta         = (uint32_t*)carve((size_t)TT * CAP * 4, 256);
  (void)ws_size; (void)out_size; (void)in_sizes; (void)n_in;

  hipMemsetAsync(bucket_count, 0, TT * 4, stream);
  scan_kernel<<<(HWPIX + 255) / 256, 256, 0, stream>>>(images, npol, bucket_count, keys, meta);
  pixel_prefix<<<TT, 256, 0, stream>>>(npol, pixpre, frame_total);
  small_scans<<<1, 64, 0, stream>>>(bucket_count, bucket_base, frame_total, frame_base);
  dim3 g4(CAP / 256, TT);
  sort_tiles<<<g4, 256, 0, stream>>>(keys, meta, bucket_count);
  rank_scatter<<<g4, 256, 0, stream>>>(keys, meta, bucket_count, bucket_base, out);
  invalid_scatter<<<(uint32_t)((NSLOTS + 255) / 256), 256, 0, stream>>>(npol, pixpre, frame_base, out);
}

// Round 6
// 384.637 us; speedup vs baseline: 22.8135x; 1.4508x over previous
//
#include <hip/hip_runtime.h>
#include <stdint.h>

#define TT 48
#define HH 180
#define WW 240
#define KCAP 4
#define HWPIX (HH*WW)                   // 43200
#define NSLOTS ((size_t)TT*HWPIX*KCAP)  // 8294400
#define CAP 16384
#define TS_STEP 33333
#define NCHUNK 169                      // ceil(43200/256)

// ---------------- Kernel 1: per-pixel serial ESIM scan, lockstep frames, LDS-aggregated slot reservation ----------------
// Fast path: bucket b in {t-1,t,t+1} -> LDS counter aggregation, 1 global atomic per (WG,bucket).
// Rare path: frac << 0 (tiny denom + ref/img_prev residual) -> bucket far below t -> per-event global atomic.
__global__ void scan_kernel(const float* __restrict__ images,
                            uint8_t* __restrict__ npol, uint32_t* __restrict__ bucket_count,
                            uint64_t* __restrict__ keys, uint32_t* __restrict__ meta) {
#pragma clang fp contract(off)
  __shared__ uint32_t lcnt[4];
  __shared__ uint32_t gbase[4];
  int tid = threadIdx.x;
  int p = blockIdx.x * blockDim.x + tid;
  bool active = p < HWPIX;

  float ref = 0.0f, img_prev = 0.0f;
  if (active) { ref = images[p]; img_prev = ref; }   // init_ref = images[0]

  for (int t = 0; t < TT; ++t) {
    if (tid < 4) lcnt[tid] = 0;
    __syncthreads();

    int ni = 0;
    float pol = 0.0f;
    uint64_t ek[KCAP]; uint32_t em[KCAP]; uint32_t eli[KCAP]; uint32_t esl[KCAP]; int eb[KCAP];

    if (active) {
      float img = images[(size_t)t * HWPIX + p];
      float diff = img - ref;
      pol = (diff > 0.0f) ? 1.0f : ((diff < 0.0f) ? -1.0f : 0.0f);
      float n = floorf(fabsf(diff) / 0.2f);     // IEEE float div, matches jnp
      ni = (int)n;
      int pc = (pol > 0.0f) ? 1 : ((pol < 0.0f) ? 2 : 0);
      npol[(size_t)t * HWPIX + p] = (uint8_t)(ni | (pc << 3));

      if (ni > 0) {                              // only possible for t >= 1
        float denom = img - img_prev;
        double tsprev = (double)((t - 1) * TS_STEP);   // exact
        double delta = (double)TS_STEP;                // exact
#pragma unroll
        for (int k = 1; k <= KCAP; ++k) {
          if (k <= ni) {
            float kct = (float)k * 0.2f;
            float v = ref + pol * kct;           // crossed level (no FMA)
            float qv = v - img_prev;
            float frac = (denom == 0.0f) ? 0.0f : (qv / denom);
            double t_ev = tsprev + (double)frac * delta;   // no FMA

            // bucket by VALUE: first b with ts[b-1] < t_ev <= ts[b]; frac can be << 0!
            int b = t;
            while (b > 0 && t_ev <= (double)((b - 1) * TS_STEP)) --b;
            while (b < TT - 1 && t_ev > (double)(b * TS_STEP)) ++b;

            uint64_t ub = (uint64_t)__double_as_longlong(t_ev);
            uint64_t key = (ub & 0x8000000000000000ULL) ? ~ub : (ub ^ 0x8000000000000000ULL);
            uint32_t gidx = (((uint32_t)t * HWPIX + (uint32_t)p) << 2) + (uint32_t)(k - 1);
            ek[k - 1] = key;
            em[k - 1] = gidx | ((pol < 0.0f ? 1u : 0u) << 23);
            eb[k - 1] = b;
            int li = b - (t - 1);
            if (li >= 0 && li <= 2) {
              eli[k - 1] = (uint32_t)li;
              esl[k - 1] = atomicAdd(&lcnt[li], 1u);            // LDS atomic: fast
            } else {
              eli[k - 1] = 3u;                                   // rare far-bucket fallback
              esl[k - 1] = atomicAdd(&bucket_count[b], 1u);      // per-event global atomic
            }
          }
        }
      }
      float nct = n * 0.2f;
      ref = ref + pol * nct;                    // new_ref (no FMA)
      img_prev = img;
    }
    __syncthreads();

    if (tid < 3) {                               // one global atomic per (WG, near-bucket)
      int b = t - 1 + tid;
      uint32_t c = lcnt[tid];
      uint32_t g = 0;
      if (c > 0 && b >= 0 && b < TT) g = atomicAdd(&bucket_count[b], c);
      gbase[tid] = g;
    }
    __syncthreads();

#pragma unroll
    for (int k = 0; k < KCAP; ++k) {
      if (k < ni) {
        uint32_t li = eli[k];
        uint32_t s = (li == 3u) ? esl[k] : (gbase[li] + esl[k]);
        int b = eb[k];
        if (s < CAP) {
          keys[(size_t)b * CAP + s] = ek[k];
          meta[(size_t)b * CAP + s] = em[k];
        }
      }
    }
  }
}

// ---------------- Kernel 2a: per-chunk shuffle scan: chunk-local exclusive prefix + chunk totals ----------------
// grid (NCHUNK, TT); 2 barriers per block instead of 169 serial chunk scans per frame.
__global__ void chunk_scan(const uint8_t* __restrict__ npol, uint32_t* __restrict__ pixpre,
                           uint32_t* __restrict__ chunk_sum) {
  int f = blockIdx.y;
  int c = blockIdx.x;
  int tid = threadIdx.x;
  int i = c * 256 + tid;                     // pixel within frame
  uint32_t v = (i < HWPIX) ? (uint32_t)(npol[(size_t)f * HWPIX + i] & 7u) : 0u;
  uint32_t lane = (uint32_t)(tid & 63);
  int w = tid >> 6;
  uint32_t x = v;
#pragma unroll
  for (int d = 1; d < 64; d <<= 1) {
    uint32_t y = __shfl_up(x, d, 64);
    if (lane >= (uint32_t)d) x += y;
  }                                          // x = inclusive scan within wave
  __shared__ uint32_t wsum[4];
  if (lane == 63) wsum[w] = x;
  __syncthreads();
  uint32_t wb = 0;
#pragma unroll
  for (int j = 0; j < 4; ++j) if (j < w) wb += wsum[j];
  uint32_t incl = x + wb;
  if (i < HWPIX) pixpre[(size_t)f * HWPIX + i] = incl - v;   // chunk-local exclusive prefix
  if (tid == 255) chunk_sum[f * NCHUNK + c] = incl;          // chunk total
}

// ---------------- Kernel 2b: per-frame scan of 169 chunk totals -> chunk_base, frame_total ----------------
__global__ void chunk_base_scan(const uint32_t* __restrict__ chunk_sum, uint32_t* __restrict__ chunk_base,
                                uint32_t* __restrict__ frame_total) {
  int f = blockIdx.x;
  int tid = threadIdx.x;
  uint32_t v = (tid < NCHUNK) ? chunk_sum[f * NCHUNK + tid] : 0u;
  uint32_t lane = (uint32_t)(tid & 63);
  int w = tid >> 6;
  uint32_t x = v;
#pragma unroll
  for (int d = 1; d < 64; d <<= 1) {
    uint32_t y = __shfl_up(x, d, 64);
    if (lane >= (uint32_t)d) x += y;
  }
  __shared__ uint32_t wsum[4];
  if (lane == 63) wsum[w] = x;
  __syncthreads();
  uint32_t wb = 0;
#pragma unroll
  for (int j = 0; j < 4; ++j) if (j < w) wb += wsum[j];
  uint32_t incl = x + wb;
  if (tid < NCHUNK) chunk_base[f * NCHUNK + tid] = incl - v;  // exclusive prefix of chunk sums
  if (tid == 255) frame_total[f] = incl;                      // frame total
}

// ---------------- Kernel 3: tiny serial scans (48 elements each) ----------------
__global__ void small_scans(const uint32_t* __restrict__ bucket_count, uint32_t* __restrict__ bucket_base,
                            const uint32_t* __restrict__ frame_total, uint32_t* __restrict__ frame_base) {
  if (threadIdx.x == 0 && blockIdx.x == 0) {
    uint32_t s = 0;
    for (int i = 0; i < TT; ++i) {
      bucket_base[i] = s;
      uint32_t c = bucket_count[i]; if (c > CAP) c = CAP;
      s += c;
    }
    bucket_base[TT] = s;
    s = 0;
    for (int i = 0; i < TT; ++i) { frame_base[i] = s; s += frame_total[i]; }
    frame_base[TT] = s;
  }
}

// ---------------- Kernel 4a: bitonic-sort each 256-element tile of each bucket in-place (by key, tie gidx) ----------------
__global__ void sort_tiles(uint64_t* __restrict__ keys, uint32_t* __restrict__ meta,
                           const uint32_t* __restrict__ bucket_count) {
  int b = blockIdx.y;
  uint32_t m = bucket_count[b]; if (m > CAP) m = CAP;
  uint32_t ntiles = (m + 255u) >> 8;
  if (blockIdx.x >= ntiles) return;
  __shared__ uint64_t sk[256];
  __shared__ uint32_t sm[256];
  int tid = threadIdx.x;
  uint32_t e = blockIdx.x * 256u + (uint32_t)tid;
  bool have = e < m;
  sk[tid] = have ? keys[(size_t)b * CAP + e] : ~0ULL;      // sentinel > any real key (real key never all-ones)
  sm[tid] = have ? meta[(size_t)b * CAP + e] : 0x7FFFFFu;
  __syncthreads();
  for (int kk = 2; kk <= 256; kk <<= 1) {
    for (int j = kk >> 1; j > 0; j >>= 1) {
      int l = tid ^ j;
      if (l > tid) {
        uint64_t ka = sk[tid], kb = sk[l];
        uint32_t ma = sm[tid], mb = sm[l];
        uint32_t ia = ma & 0x7FFFFFu, ib = mb & 0x7FFFFFu;
        bool a_gt = (ka > kb) || (ka == kb && ia > ib);
        bool a_lt = (ka < kb) || (ka == kb && ia < ib);
        bool desc = (tid & kk) != 0;
        bool dosw = desc ? a_lt : a_gt;
        if (dosw) { sk[tid] = kb; sk[l] = ka; sm[tid] = mb; sm[l] = ma; }
      }
      __syncthreads();
    }
  }
  keys[(size_t)b * CAP + e] = sk[tid];   // e < CAP always; slots >= m never read downstream
  meta[(size_t)b * CAP + e] = sm[tid];
}

// ---------------- Kernel 4b: rank via per-tile binary search (tiles sorted), then scatter valid events ----------------
__global__ void rank_scatter(const uint64_t* __restrict__ keys, const uint32_t* __restrict__ meta,
                             const uint32_t* __restrict__ bucket_count, const uint32_t* __restrict__ bucket_base,
                             int32_t* __restrict__ out) {
  int b = blockIdx.y;
  uint32_t m = bucket_count[b]; if (m > CAP) m = CAP;
  uint32_t ntiles = (m + 255u) >> 8;
  if (blockIdx.x >= ntiles) return;
  __shared__ uint64_t sk[256];
  __shared__ uint32_t sm[256];
  uint32_t e = blockIdx.x * 256u + threadIdx.x;
  bool have = e < m;
  uint64_t myk = 0; uint32_t mym = 0;
  if (have) { myk = keys[(size_t)b * CAP + e]; mym = meta[(size_t)b * CAP + e]; }
  uint32_t myidx = mym & 0x7FFFFFu;
  uint32_t rank = 0;
  for (uint32_t t2 = 0; t2 < ntiles; ++t2) {
    uint32_t j = t2 * 256u + threadIdx.x;
    sk[threadIdx.x] = (j < m) ? keys[(size_t)b * CAP + j] : ~0ULL;
    sm[threadIdx.x] = (j < m) ? meta[(size_t)b * CAP + j] : 0x7FFFFFu;
    __syncthreads();
    if (have) {
      // lower_bound of (myk, myidx) in sorted 256-tile; sentinels never counted
      uint32_t lo = 0, hi = 256;
      while (lo < hi) {
        uint32_t mid = (lo + hi) >> 1;
        uint64_t kj = sk[mid];
        uint32_t ij = sm[mid] & 0x7FFFFFu;
        bool less = (kj < myk) || (kj == myk && ij < myidx);
        lo = less ? mid + 1u : lo;
        hi = less ? hi : mid;
      }
      rank += lo;     // own tile contributes exactly my in-tile position
    }
    __syncthreads();
  }
  if (have) {
    uint32_t pos = bucket_base[b] + rank;
    uint64_t ub = (myk & 0x8000000000000000ULL) ? (myk ^ 0x8000000000000000ULL) : ~myk;
    double t_ev = __longlong_as_double((long long)ub);
    uint32_t pix = (myidx >> 2) % HWPIX;
    uint32_t x = pix % WW, y = pix / WW;
    int32_t pval = ((mym >> 23) & 1u) ? -1 : 1;
    long long ti = (long long)t_ev;           // trunc-toward-zero == astype(int64) for t_ev >= 0
    out[pos]              = (int32_t)x;
    out[NSLOTS + pos]     = (int32_t)y;
    out[2 * NSLOTS + pos] = (int32_t)ti;
    out[3 * NSLOTS + pos] = pval;
    out[4 * NSLOTS + pos] = 1;
  }
}

// ---------------- Kernel 5: invalid slots -> tail, original flat order ----------------
__global__ void invalid_scatter(const uint8_t* __restrict__ npol, const uint32_t* __restrict__ pixpre,
                                const uint32_t* __restrict__ chunk_base, const uint32_t* __restrict__ frame_base,
                                int32_t* __restrict__ out) {
  uint32_t s = blockIdx.x * blockDim.x + threadIdx.x;
  if (s >= (uint32_t)NSLOTS) return;
  uint32_t k = (s & 3u) + 1u;
  uint32_t tp = s >> 2;
  uint32_t t = tp / HWPIX;
  uint32_t pix = tp - t * HWPIX;
  uint8_t bb = npol[tp];
  uint32_t n = bb & 7u;
  if (k <= n) return;                          // valid slot, handled by rank_scatter
  uint32_t nvalid_total = frame_base[TT];
  uint32_t vb = frame_base[t] + chunk_base[t * NCHUNK + (pix >> 8)] + pixpre[tp] + min(k - 1u, n);
  uint32_t pos = nvalid_total + (s - vb);
  uint32_t x = pix % WW, y = pix / WW;
  uint32_t pc = (bb >> 3) & 3u;
  int32_t pval = (pc == 1u) ? 1 : ((pc == 2u) ? -1 : 0);
  out[pos]              = (int32_t)x;
  out[NSLOTS + pos]     = (int32_t)y;
  out[2 * NSLOTS + pos] = 0;
  out[3 * NSLOTS + pos] = pval;
  out[4 * NSLOTS + pos] = 0;
}

extern "C" void kernel_launch(void* const* d_in, const int* in_sizes, int n_in,
                              void* d_out, int out_size, void* d_ws, size_t ws_size,
                              hipStream_t stream) {
  const float* images = (const float*)d_in[0];
  int32_t* out = (int32_t*)d_out;

  uint8_t* base = (uint8_t*)d_ws;
  size_t off = 0;
  auto carve = [&](size_t bytes, size_t align) -> void* {
    off = (off + align - 1) & ~(align - 1);
    void* p = base + off; off += bytes; return p;
  };
  uint32_t* bucket_count = (uint32_t*)carve(TT * 4, 256);
  uint32_t* bucket_base  = (uint32_t*)carve((TT + 1) * 4, 256);
  uint32_t* frame_total  = (uint32_t*)carve(TT * 4, 256);
  uint32_t* frame_base   = (uint32_t*)carve((TT + 1) * 4, 256);
  uint8_t*  npol         = (uint8_t*) carve((size_t)TT * HWPIX, 256);
  uint32_t* pixpre       = (uint32_t*)carve((size_t)TT * HWPIX * 4, 256);
  uint32_t* chunk_sum    = (uint32_t*)carve((size_t)TT * NCHUNK * 4, 256);
  uint32_t* chunk_base   = (uint32_t*)carve((size_t)TT * NCHUNK * 4, 256);
  uint64_t* keys         = (uint64_t*)carve((size_t)TT * CAP * 8, 256);
  uint32_t* meta         = (uint32_t*)carve((size_t)TT * CAP * 4, 256);
  (void)ws_size; (void)out_size; (void)in_sizes; (void)n_in;

  hipMemsetAsync(bucket_count, 0, TT * 4, stream);
  scan_kernel<<<(HWPIX + 255) / 256, 256, 0, stream>>>(images, npol, bucket_count, keys, meta);
  dim3 g2(NCHUNK, TT);
  chunk_scan<<<g2, 256, 0, stream>>>(npol, pixpre, chunk_sum);
  chunk_base_scan<<<TT, 256, 0, stream>>>(chunk_sum, chunk_base, frame_total);
  small_scans<<<1, 64, 0, stream>>>(bucket_count, bucket_base, frame_total, frame_base);
  dim3 g4(CAP / 256, TT);
  sort_tiles<<<g4, 256, 0, stream>>>(keys, meta, bucket_count);
  rank_scatter<<<g4, 256, 0, stream>>>(keys, meta, bucket_count, bucket_base, out);
  invalid_scatter<<<(uint32_t)((NSLOTS + 255) / 256), 256, 0, stream>>>(npol, pixpre, chunk_base, frame_base, out);
}

// Round 7
// 304.497 us; speedup vs baseline: 28.8177x; 1.2632x over previous
//
#include <hip/hip_runtime.h>
#include <stdint.h>

#define TT 48
#define HH 180
#define WW 240
#define KCAP 4
#define HWPIX (HH*WW)                   // 43200
#define NSLOTS ((size_t)TT*HWPIX*KCAP)  // 8294400
#define CAP 16384
#define TS_STEP 33333
#define NCHUNK 169                      // ceil(43200/256)
#define STILE 2048                      // sorted-tile size
#define SPAD(i) ((i) + ((i) >> 4) + ((i) >> 8))   // LDS anti-bank-conflict pad for bitonic strides

// ---------------- Kernel 1: per-pixel serial ESIM scan, lockstep frames, LDS-aggregated slot reservation ----------------
// Fast path: bucket b in {t-1,t,t+1} -> LDS counter aggregation, 1 global atomic per (WG,bucket).
// Rare path: frac << 0 (tiny denom + ref/img_prev residual) -> bucket far below t -> per-event global atomic.
__global__ void scan_kernel(const float* __restrict__ images,
                            uint8_t* __restrict__ npol, uint32_t* __restrict__ bucket_count,
                            uint64_t* __restrict__ keys, uint32_t* __restrict__ meta) {
#pragma clang fp contract(off)
  __shared__ uint32_t lcnt[4];
  __shared__ uint32_t gbase[4];
  int tid = threadIdx.x;
  int p = blockIdx.x * blockDim.x + tid;
  bool active = p < HWPIX;

  float ref = 0.0f, img_prev = 0.0f;
  if (active) { ref = images[p]; img_prev = ref; }   // init_ref = images[0]

  for (int t = 0; t < TT; ++t) {
    if (tid < 4) lcnt[tid] = 0;
    __syncthreads();

    int ni = 0;
    float pol = 0.0f;
    uint64_t ek[KCAP]; uint32_t em[KCAP]; uint32_t eli[KCAP]; uint32_t esl[KCAP]; int eb[KCAP];

    if (active) {
      float img = images[(size_t)t * HWPIX + p];
      float diff = img - ref;
      pol = (diff > 0.0f) ? 1.0f : ((diff < 0.0f) ? -1.0f : 0.0f);
      float n = floorf(fabsf(diff) / 0.2f);     // IEEE float div, matches jnp
      ni = (int)n;
      int pc = (pol > 0.0f) ? 1 : ((pol < 0.0f) ? 2 : 0);
      npol[(size_t)t * HWPIX + p] = (uint8_t)(ni | (pc << 3));

      if (ni > 0) {                              // only possible for t >= 1
        float denom = img - img_prev;
        double tsprev = (double)((t - 1) * TS_STEP);   // exact
        double delta = (double)TS_STEP;                // exact
#pragma unroll
        for (int k = 1; k <= KCAP; ++k) {
          if (k <= ni) {
            float kct = (float)k * 0.2f;
            float v = ref + pol * kct;           // crossed level (no FMA)
            float qv = v - img_prev;
            float frac = (denom == 0.0f) ? 0.0f : (qv / denom);
            double t_ev = tsprev + (double)frac * delta;   // no FMA

            // bucket by VALUE: first b with ts[b-1] < t_ev <= ts[b]; frac can be << 0!
            int b = t;
            while (b > 0 && t_ev <= (double)((b - 1) * TS_STEP)) --b;
            while (b < TT - 1 && t_ev > (double)(b * TS_STEP)) ++b;

            uint64_t ub = (uint64_t)__double_as_longlong(t_ev);
            uint64_t key = (ub & 0x8000000000000000ULL) ? ~ub : (ub ^ 0x8000000000000000ULL);
            uint32_t gidx = (((uint32_t)t * HWPIX + (uint32_t)p) << 2) + (uint32_t)(k - 1);
            ek[k - 1] = key;
            em[k - 1] = gidx | ((pol < 0.0f ? 1u : 0u) << 23);
            eb[k - 1] = b;
            int li = b - (t - 1);
            if (li >= 0 && li <= 2) {
              eli[k - 1] = (uint32_t)li;
              esl[k - 1] = atomicAdd(&lcnt[li], 1u);            // LDS atomic: fast
            } else {
              eli[k - 1] = 3u;                                   // rare far-bucket fallback
              esl[k - 1] = atomicAdd(&bucket_count[b], 1u);      // per-event global atomic
            }
          }
        }
      }
      float nct = n * 0.2f;
      ref = ref + pol * nct;                    // new_ref (no FMA)
      img_prev = img;
    }
    __syncthreads();

    if (tid < 3) {                               // one global atomic per (WG, near-bucket)
      int b = t - 1 + tid;
      uint32_t c = lcnt[tid];
      uint32_t g = 0;
      if (c > 0 && b >= 0 && b < TT) g = atomicAdd(&bucket_count[b], c);
      gbase[tid] = g;
    }
    __syncthreads();

#pragma unroll
    for (int k = 0; k < KCAP; ++k) {
      if (k < ni) {
        uint32_t li = eli[k];
        uint32_t s = (li == 3u) ? esl[k] : (gbase[li] + esl[k]);
        int b = eb[k];
        if (s < CAP) {
          keys[(size_t)b * CAP + s] = ek[k];
          meta[(size_t)b * CAP + s] = em[k];
        }
      }
    }
  }
}

// ---------------- Kernel 2a: per-chunk shuffle scan: chunk-local exclusive prefix + chunk totals ----------------
__global__ void chunk_scan(const uint8_t* __restrict__ npol, uint32_t* __restrict__ pixpre,
                           uint32_t* __restrict__ chunk_sum) {
  int f = blockIdx.y;
  int c = blockIdx.x;
  int tid = threadIdx.x;
  int i = c * 256 + tid;                     // pixel within frame
  uint32_t v = (i < HWPIX) ? (uint32_t)(npol[(size_t)f * HWPIX + i] & 7u) : 0u;
  uint32_t lane = (uint32_t)(tid & 63);
  int w = tid >> 6;
  uint32_t x = v;
#pragma unroll
  for (int d = 1; d < 64; d <<= 1) {
    uint32_t y = __shfl_up(x, d, 64);
    if (lane >= (uint32_t)d) x += y;
  }                                          // x = inclusive scan within wave
  __shared__ uint32_t wsum[4];
  if (lane == 63) wsum[w] = x;
  __syncthreads();
  uint32_t wb = 0;
#pragma unroll
  for (int j = 0; j < 4; ++j) if (j < w) wb += wsum[j];
  uint32_t incl = x + wb;
  if (i < HWPIX) pixpre[(size_t)f * HWPIX + i] = incl - v;   // chunk-local exclusive prefix
  if (tid == 255) chunk_sum[f * NCHUNK + c] = incl;          // chunk total
}

// ---------------- Kernel 2b: per-frame scan of 169 chunk totals -> chunk_base, frame_total ----------------
__global__ void chunk_base_scan(const uint32_t* __restrict__ chunk_sum, uint32_t* __restrict__ chunk_base,
                                uint32_t* __restrict__ frame_total) {
  int f = blockIdx.x;
  int tid = threadIdx.x;
  uint32_t v = (tid < NCHUNK) ? chunk_sum[f * NCHUNK + tid] : 0u;
  uint32_t lane = (uint32_t)(tid & 63);
  int w = tid >> 6;
  uint32_t x = v;
#pragma unroll
  for (int d = 1; d < 64; d <<= 1) {
    uint32_t y = __shfl_up(x, d, 64);
    if (lane >= (uint32_t)d) x += y;
  }
  __shared__ uint32_t wsum[4];
  if (lane == 63) wsum[w] = x;
  __syncthreads();
  uint32_t wb = 0;
#pragma unroll
  for (int j = 0; j < 4; ++j) if (j < w) wb += wsum[j];
  uint32_t incl = x + wb;
  if (tid < NCHUNK) chunk_base[f * NCHUNK + tid] = incl - v;  // exclusive prefix of chunk sums
  if (tid == 255) frame_total[f] = incl;                      // frame total
}

// ---------------- Kernel 3: tiny serial scans (48 elements each) ----------------
__global__ void small_scans(const uint32_t* __restrict__ bucket_count, uint32_t* __restrict__ bucket_base,
                            const uint32_t* __restrict__ frame_total, uint32_t* __restrict__ frame_base) {
  if (threadIdx.x == 0 && blockIdx.x == 0) {
    uint32_t s = 0;
    for (int i = 0; i < TT; ++i) {
      bucket_base[i] = s;
      uint32_t c = bucket_count[i]; if (c > CAP) c = CAP;
      s += c;
    }
    bucket_base[TT] = s;
    s = 0;
    for (int i = 0; i < TT; ++i) { frame_base[i] = s; s += frame_total[i]; }
    frame_base[TT] = s;
  }
}

// ---------------- Kernel 4a: bitonic-sort each 2048-element tile of each bucket in-place (by key, tie gidx) ----------------
// 256 threads, 4 compare-exchanges/thread/stage (independent -> ILP), padded LDS indices kill
// the power-of-2-stride bank conflicts of the bitonic network.
__global__ void sort_tiles(uint64_t* __restrict__ keys, uint32_t* __restrict__ meta,
                           const uint32_t* __restrict__ bucket_count) {
  int b = blockIdx.y;
  uint32_t m = bucket_count[b]; if (m > CAP) m = CAP;
  uint32_t tile0 = blockIdx.x * STILE;
  if (tile0 >= m) return;
  __shared__ uint64_t sk[2184];
  __shared__ uint32_t sm[2184];
  int tid = threadIdx.x;
#pragma unroll
  for (int r = 0; r < 8; ++r) {
    uint32_t i = (uint32_t)(r * 256 + tid);
    uint32_t e = tile0 + i;
    bool have = e < m;
    sk[SPAD(i)] = have ? keys[(size_t)b * CAP + e] : ~0ULL;    // sentinel > any real key
    sm[SPAD(i)] = have ? meta[(size_t)b * CAP + e] : 0x7FFFFFu;
  }
  __syncthreads();
  for (uint32_t kk = 2; kk <= STILE; kk <<= 1) {
    for (uint32_t j = kk >> 1; j > 0; j >>= 1) {
#pragma unroll 4
      for (int r = 0; r < 4; ++r) {
        uint32_t idx = (uint32_t)(r * 256 + tid);
        uint32_t i1 = ((idx & ~(j - 1u)) << 1) | (idx & (j - 1u));
        uint32_t i2 = i1 + j;
        uint32_t p1 = SPAD(i1), p2 = SPAD(i2);
        uint64_t ka = sk[p1], kb2 = sk[p2];
        uint32_t ma = sm[p1], mb = sm[p2];
        bool agt = (ka > kb2) || (ka == kb2 && (ma & 0x7FFFFFu) > (mb & 0x7FFFFFu));
        bool desc = (i1 & kk) != 0;
        if (agt != desc) { sk[p1] = kb2; sk[p2] = ka; sm[p1] = mb; sm[p2] = ma; }
      }
      __syncthreads();
    }
  }
#pragma unroll
  for (int r = 0; r < 8; ++r) {
    uint32_t i = (uint32_t)(r * 256 + tid);
    uint32_t e = tile0 + i;                    // e < CAP always (CAP multiple of STILE)
    keys[(size_t)b * CAP + e] = sk[SPAD(i)];
    meta[(size_t)b * CAP + e] = sm[SPAD(i)];
  }
}

// ---------------- Kernel 4b: rank via per-2048-tile binary search; own tile's rank = storage index ----------------
__global__ void rank_scatter(const uint64_t* __restrict__ keys, const uint32_t* __restrict__ meta,
                             const uint32_t* __restrict__ bucket_count, const uint32_t* __restrict__ bucket_base,
                             int32_t* __restrict__ out) {
  int b = blockIdx.y;
  uint32_t m = bucket_count[b]; if (m > CAP) m = CAP;
  if (blockIdx.x * 256u >= m) return;
  uint32_t ntiles = (m + STILE - 1u) / STILE;
  uint32_t own_tile = (blockIdx.x * 256u) >> 11;      // block lies inside one 2048-tile
  __shared__ uint64_t sk[STILE];
  __shared__ uint32_t sm[STILE];
  uint32_t e = blockIdx.x * 256u + threadIdx.x;
  bool have = e < m;
  uint64_t myk = 0; uint32_t mym = 0;
  if (have) { myk = keys[(size_t)b * CAP + e]; mym = meta[(size_t)b * CAP + e]; }
  uint32_t myidx = mym & 0x7FFFFFu;
  uint32_t rank = have ? (e & (STILE - 1u)) : 0u;     // own sorted tile: rank = in-tile position
  for (uint32_t t2 = 0; t2 < ntiles; ++t2) {
    if (t2 == own_tile) continue;                     // block-uniform skip
#pragma unroll
    for (int r = 0; r < 8; ++r) {
      uint32_t i = (uint32_t)(r * 256 + threadIdx.x);
      uint32_t j = t2 * STILE + i;
      sk[i] = (j < m) ? keys[(size_t)b * CAP + j] : ~0ULL;
      sm[i] = (j < m) ? meta[(size_t)b * CAP + j] : 0x7FFFFFu;
    }
    __syncthreads();
    if (have) {
      uint32_t lo = 0, hi = STILE;                    // lower_bound of (myk, myidx); 11 probes
      while (lo < hi) {
        uint32_t mid = (lo + hi) >> 1;
        uint64_t kj = sk[mid];
        uint32_t ij = sm[mid] & 0x7FFFFFu;
        bool less = (kj < myk) || (kj == myk && ij < myidx);
        lo = less ? mid + 1u : lo;
        hi = less ? hi : mid;
      }
      rank += lo;
    }
    __syncthreads();
  }
  if (have) {
    uint32_t pos = bucket_base[b] + rank;
    uint64_t ub = (myk & 0x8000000000000000ULL) ? (myk ^ 0x8000000000000000ULL) : ~myk;
    double t_ev = __longlong_as_double((long long)ub);
    uint32_t pix = (myidx >> 2) % HWPIX;
    uint32_t x = pix % WW, y = pix / WW;
    int32_t pval = ((mym >> 23) & 1u) ? -1 : 1;
    long long ti = (long long)t_ev;           // trunc-toward-zero == astype(int64) for t_ev >= 0
    out[pos]              = (int32_t)x;
    out[NSLOTS + pos]     = (int32_t)y;
    out[2 * NSLOTS + pos] = (int32_t)ti;
    out[3 * NSLOTS + pos] = pval;
    out[4 * NSLOTS + pos] = 1;
  }
}

// ---------------- Kernel 5: invalid slots -> tail, original flat order ----------------
__global__ void invalid_scatter(const uint8_t* __restrict__ npol, const uint32_t* __restrict__ pixpre,
                                const uint32_t* __restrict__ chunk_base, const uint32_t* __restrict__ frame_base,
                                int32_t* __restrict__ out) {
  uint32_t s = blockIdx.x * blockDim.x + threadIdx.x;
  if (s >= (uint32_t)NSLOTS) return;
  uint32_t k = (s & 3u) + 1u;
  uint32_t tp = s >> 2;
  uint32_t t = tp / HWPIX;
  uint32_t pix = tp - t * HWPIX;
  uint8_t bb = npol[tp];
  uint32_t n = bb & 7u;
  if (k <= n) return;                          // valid slot, handled by rank_scatter
  uint32_t nvalid_total = frame_base[TT];
  uint32_t vb = frame_base[t] + chunk_base[t * NCHUNK + (pix >> 8)] + pixpre[tp] + min(k - 1u, n);
  uint32_t pos = nvalid_total + (s - vb);
  uint32_t x = pix % WW, y = pix / WW;
  uint32_t pc = (bb >> 3) & 3u;
  int32_t pval = (pc == 1u) ? 1 : ((pc == 2u) ? -1 : 0);
  out[pos]              = (int32_t)x;
  out[NSLOTS + pos]     = (int32_t)y;
  out[2 * NSLOTS + pos] = 0;
  out[3 * NSLOTS + pos] = pval;
  out[4 * NSLOTS + pos] = 0;
}

extern "C" void kernel_launch(void* const* d_in, const int* in_sizes, int n_in,
                              void* d_out, int out_size, void* d_ws, size_t ws_size,
                              hipStream_t stream) {
  const float* images = (const float*)d_in[0];
  int32_t* out = (int32_t*)d_out;

  uint8_t* base = (uint8_t*)d_ws;
  size_t off = 0;
  auto carve = [&](size_t bytes, size_t align) -> void* {
    off = (off + align - 1) & ~(align - 1);
    void* p = base + off; off += bytes; return p;
  };
  uint32_t* bucket_count = (uint32_t*)carve(TT * 4, 256);
  uint32_t* bucket_base  = (uint32_t*)carve((TT + 1) * 4, 256);
  uint32_t* frame_total  = (uint32_t*)carve(TT * 4, 256);
  uint32_t* frame_base   = (uint32_t*)carve((TT + 1) * 4, 256);
  uint8_t*  npol         = (uint8_t*) carve((size_t)TT * HWPIX, 256);
  uint32_t* pixpre       = (uint32_t*)carve((size_t)TT * HWPIX * 4, 256);
  uint32_t* chunk_sum    = (uint32_t*)carve((size_t)TT * NCHUNK * 4, 256);
  uint32_t* chunk_base   = (uint32_t*)carve((size_t)TT * NCHUNK * 4, 256);
  uint64_t* keys         = (uint64_t*)carve((size_t)TT * CAP * 8, 256);
  uint32_t* meta         = (uint32_t*)carve((size_t)TT * CAP * 4, 256);
  (void)ws_size; (void)out_size; (void)in_sizes; (void)n_in;

  hipMemsetAsync(bucket_count, 0, TT * 4, stream);
  scan_kernel<<<(HWPIX + 255) / 256, 256, 0, stream>>>(images, npol, bucket_count, keys, meta);
  dim3 g2(NCHUNK, TT);
  chunk_scan<<<g2, 256, 0, stream>>>(npol, pixpre, chunk_sum);
  chunk_base_scan<<<TT, 256, 0, stream>>>(chunk_sum, chunk_base, frame_total);
  small_scans<<<1, 64, 0, stream>>>(bucket_count, bucket_base, frame_total, frame_base);
  dim3 gs(CAP / STILE, TT);
  sort_tiles<<<gs, 256, 0, stream>>>(keys, meta, bucket_count);
  dim3 g4(CAP / 256, TT);
  rank_scatter<<<g4, 256, 0, stream>>>(keys, meta, bucket_count, bucket_base, out);
  invalid_scatter<<<(uint32_t)((NSLOTS + 255) / 256), 256, 0, stream>>>(npol, pixpre, chunk_base, frame_base, out);
}